// Round 14
// baseline (455.772 us; speedup 1.0000x reference)
//
#include <hip/hip_runtime.h>

using u16    = unsigned short;
using u32    = unsigned int;
using u64    = unsigned long long;
using bf16x8 = __attribute__((ext_vector_type(8))) short;
using f32x4  = __attribute__((ext_vector_type(4))) float;
using u16x4  = __attribute__((ext_vector_type(4))) u16;

#define NB   16
#define PP   2048
#define CC   64
#define KK   16
#define MROWS (NB*PP*KK)   /* 524288 */
#define NPTS  (NB*PP)      /* 32768  */

__device__ __forceinline__ float b2f(u16 u) { return __uint_as_float(((unsigned)u) << 16); }
__device__ __forceinline__ u16 f2b(float f) {
  unsigned u = __float_as_uint(f);
  return (u16)((u + 0x7fffu + ((u >> 16) & 1u)) >> 16);
}

// order-preserving (d, qi) -> u64 key: smaller key == smaller d, tie -> smaller qi (EXACT)
__device__ __forceinline__ u64 dkey(float d, int qi) {
  unsigned u = __float_as_uint(d);
  u = u ^ (((unsigned)((int)u >> 31)) | 0x80000000u);
  return ((u64)u << 32) | (unsigned)qi;
}

template<bool UP>
__device__ __forceinline__ void ce(u64 &a, u64 &b) {
  const bool lt = a < b;
  const u64 lo = lt ? a : b;
  const u64 hi = lt ? b : a;
  if (UP) { a = lo; b = hi; } else { a = hi; b = lo; }
}

// full bitonic sort, ascending
__device__ __forceinline__ void sort16(u64 (&v)[16]) {
  #pragma unroll
  for (int k = 2; k <= 16; k <<= 1) {
    #pragma unroll
    for (int j = k >> 1; j > 0; j >>= 1) {
      #pragma unroll
      for (int i = 0; i < 16; ++i) {
        const int l = i ^ j;
        if (l > i) {
          if ((i & k) == 0) ce<true>(v[i], v[l]);
          else              ce<false>(v[i], v[l]);
        }
      }
    }
  }
}

// dl (sorted asc) <- lowest 16 of union(dl, nb), nb sorted asc; result sorted asc
__device__ __forceinline__ void merge16(u64 (&dl)[16], const u64 (&nb)[16]) {
  u64 t[16];
  #pragma unroll
  for (int s = 0; s < 16; ++s) {
    const u64 a = dl[s], b = nb[15 - s];
    t[s] = a < b ? a : b;                 // bitonic sequence of the 16 smallest
  }
  #pragma unroll
  for (int j = 8; j > 0; j >>= 1) {
    #pragma unroll
    for (int i = 0; i < 16; ++i) {
      const int l = i ^ j;
      if (l > i) ce<true>(t[i], t[l]);
    }
  }
  #pragma unroll
  for (int s = 0; s < 16; ++s) dl[s] = t[s];
}

// ---------------- prep: features (N,C,P) -> Xb (h plane, bf16), X3 (m,l planes), r ----------------
// 3-way bf16 split: x = h + m + l + eps, |eps| <~ 2^-27 |x| (each residual exact by Sterbenz).
__global__ __launch_bounds__(256) void prep_k(const float* __restrict__ F,
                                              u16* __restrict__ Xb,
                                              u16* __restrict__ X3,
                                              float* __restrict__ r) {
  int gidx = blockIdx.x * 256 + threadIdx.x;      // 0..32767
  int n = gidx >> 11, p = gidx & 2047;
  const float* src = F + (size_t)n * CC * PP + p;
  float rr = 0.f;
  u16 ha[CC], ma[CC], la[CC];
  #pragma unroll
  for (int c = 0; c < CC; ++c) {
    const float x = src[(size_t)c * PP];
    rr += x * x;
    const u16 h = f2b(x);
    const float eh = x - b2f(h);          // exact
    const u16 m = f2b(eh);
    const float el = eh - b2f(m);         // exact
    const u16 lo_ = f2b(el);
    ha[c] = h; ma[c] = m; la[c] = lo_;
  }
  u16* db = Xb + (size_t)gidx * CC;
  u16* d3 = X3 + (size_t)gidx * 128;
  #pragma unroll
  for (int c = 0; c < CC; c += 8) {
    bf16x8 wh, wm, wl;
    #pragma unroll
    for (int j = 0; j < 8; ++j) { wh[j] = (short)ha[c+j]; wm[j] = (short)ma[c+j]; wl[j] = (short)la[c+j]; }
    *(bf16x8*)(db + c)      = wh;
    *(bf16x8*)(d3 + c)      = wm;
    *(bf16x8*)(d3 + 64 + c) = wl;
  }
  r[gidx] = rr;
}

// ---------------- weight fp32 -> bf16 ----------------
__global__ __launch_bounds__(256) void cvtw_k(const float* __restrict__ w0, const float* __restrict__ w1,
                                              const float* __restrict__ w2, const float* __restrict__ wsb,
                                              u16* __restrict__ b0, u16* __restrict__ b1,
                                              u16* __restrict__ b2, u16* __restrict__ bs) {
  int i = blockIdx.x * 256 + threadIdx.x;         // 20480 total
  if (i < 8192)        b0[i]          = f2b(w0[i]);
  else if (i < 12288)  b1[i - 8192]   = f2b(w1[i - 8192]);
  else if (i < 16384)  b2[i - 12288]  = f2b(w2[i - 12288]);
  else if (i < 20480)  bs[i - 16384]  = f2b(wsb[i - 16384]);
}

// ---------------- fused KNN v9 (r12 verbatim): 256-thread WG, split-bf16 MFMA GEMM + u64 top-16 ---
// grid 2048: n = bx>>7, pb = ((bx>>2)&31)*64, qq = bx&3 -> q in [qq*512, +512), 4 tiles of 128 q.
// 4 waves: wave w owns p-rows w*16..+15 x all 128 q -> acc[8] (8 subtiles of 16x16).
// A-fragments loaded ONCE from global into registers (no Xp LDS). LDS = XqL [128][200] bf16 only;
// D [64][132] f32 and the merge area overlay it.
__global__ __launch_bounds__(256)
void knn_k(const u16* __restrict__ Xb, const u16* __restrict__ X3,
           const float* __restrict__ r, u64* __restrict__ part) {
  __shared__ u16 XqL[128 * 200];                // 51.2 KB; D + merge area overlay
  float* D  = (float*)XqL;                      // [64][132] f32 (33.8 KB)
  u64*   mb = (u64*)XqL;                        // merge area (32 KB)

  const int n  = blockIdx.x >> 7;
  const int pb = ((blockIdx.x >> 2) & 31) * 64;
  const int qq = blockIdx.x & 3;
  const int qstart = qq * 512;
  const int t  = threadIdx.x;
  const int l  = t & 63, w = t >> 6;            // wave index 0..3
  const int lo = l & 15, hi4 = l >> 4;
  const int prow = t & 63;                      // select: own row
  const int qh2  = t >> 6;                      // select: quarter of tile
  const int u4   = (prow & 7) * 4;              // select-side swizzle key

  const u16*  Xbn = Xb + (size_t)(n * PP) * CC;
  const u16*  X3n = X3 + (size_t)(n * PP) * 128;
  const float* rb = r + n * PP;

  // A-fragments direct from global, once (row = pb + w*16 + lo)
  bf16x8 ah[2], am[2], al[2];
  {
    const size_t rowb = (size_t)(pb + w * 16 + lo);
    #pragma unroll
    for (int kb = 0; kb < 2; ++kb) {
      ah[kb] = *(const bf16x8*)(Xbn + rowb * CC  + kb * 32 + hi4 * 8);
      am[kb] = *(const bf16x8*)(X3n + rowb * 128 + kb * 32 + hi4 * 8);
      al[kb] = *(const bf16x8*)(X3n + rowb * 128 + 64 + kb * 32 + hi4 * 8);
    }
  }

  u64 dl[16];
  #pragma unroll
  for (int s = 0; s < 16; ++s) dl[s] = ~0ULL;

  #pragma unroll 1
  for (int qb = qstart; qb < qstart + 512; qb += 128) {
    __syncthreads();                    // previous select readers done
    { // stage XqL [128][200]: h 1024 units (4/thread), m|l 2048 units (8/thread)
      #pragma unroll
      for (int k = 0; k < 4; ++k) {
        const int u = t + k * 256;
        const int row = u >> 3, unit = u & 7;
        *(bf16x8*)(XqL + row * 200 + unit * 8) =
          *(const bf16x8*)(Xbn + (size_t)(qb + row) * CC + unit * 8);
      }
      #pragma unroll
      for (int k = 0; k < 8; ++k) {
        const int u = t + k * 256;
        const int row = u >> 4, unit = u & 15;
        *(bf16x8*)(XqL + row * 200 + 64 + unit * 8) =
          *(const bf16x8*)(X3n + (size_t)(qb + row) * 128 + unit * 8);
      }
    }
    __syncthreads();

    f32x4 acc[8];
    #pragma unroll
    for (int Q = 0; Q < 8; ++Q) { f32x4 z = {0.f, 0.f, 0.f, 0.f}; acc[Q] = z; }

    #pragma unroll
    for (int Q = 0; Q < 8; ++Q) {
      const int qrow = Q * 16 + lo;
      #pragma unroll
      for (int kb = 0; kb < 2; ++kb) {
        const int base = qrow * 200 + kb * 32 + hi4 * 8;
        const bf16x8 bh = *(const bf16x8*)(XqL + base);
        const bf16x8 bm = *(const bf16x8*)(XqL + base + 64);
        const bf16x8 bl = *(const bf16x8*)(XqL + base + 128);
        acc[Q] = __builtin_amdgcn_mfma_f32_16x16x32_bf16(ah[kb], bh, acc[Q], 0, 0, 0);
        acc[Q] = __builtin_amdgcn_mfma_f32_16x16x32_bf16(am[kb], bh, acc[Q], 0, 0, 0);
        acc[Q] = __builtin_amdgcn_mfma_f32_16x16x32_bf16(ah[kb], bm, acc[Q], 0, 0, 0);
        acc[Q] = __builtin_amdgcn_mfma_f32_16x16x32_bf16(al[kb], bh, acc[Q], 0, 0, 0);
        acc[Q] = __builtin_amdgcn_mfma_f32_16x16x32_bf16(ah[kb], bl, acc[Q], 0, 0, 0);
        acc[Q] = __builtin_amdgcn_mfma_f32_16x16x32_bf16(am[kb], bm, acc[Q], 0, 0, 0);
      }
    }
    __syncthreads();                    // all XqL fragment reads done -> overlay D

    { // D-write: p = w*16 + hi4*4 + e (MFMA row-reg), q = Q*16 + lo (MFMA col)
      #pragma unroll
      for (int Q = 0; Q < 8; ++Q) {
        const int qloc  = Q * 16 + lo;
        const int qglob = qb + qloc;
        const float rq  = rb[qglob];
        const int bidx = qloc >> 2, qrem = qloc & 3;
        #pragma unroll
        for (int e = 0; e < 4; ++e) {
          const int p = w * 16 + hi4 * 4 + e;
          float d = rq - 2.f * acc[Q][e];
          if (qglob == pb + p) d = 3.0e38f;
          const int swz = ((bidx ^ ((p & 7) << 2)) << 2) + qrem;
          D[p * 132 + swz] = d;
        }
      }
    }
    __syncthreads();

    // select: thread scans row prow, blocks b = qh2*8..+7 as two 16-key batches
    #pragma unroll
    for (int half = 0; half < 2; ++half) {
      u64 nb[16];
      const float* drow = D + (size_t)prow * 132;
      #pragma unroll
      for (int bb = 0; bb < 4; ++bb) {
        const int b = qh2 * 8 + half * 4 + bb;
        const float4 dv = *(const float4*)(drow + ((b ^ u4) * 4));
        const int qg = qb + b * 4;
        nb[bb*4+0] = dkey(dv.x, qg+0);
        nb[bb*4+1] = dkey(dv.y, qg+1);
        nb[bb*4+2] = dkey(dv.z, qg+2);
        nb[bb*4+3] = dkey(dv.w, qg+3);
      }
      sort16(nb);
      merge16(dl, nb);
    }
  }

  // merge 4 partial sorted lists per row (threads t, t+64, t+128, t+192) via LDS
  __syncthreads();
  {
    #pragma unroll
    for (int s = 0; s < 16; ++s) mb[s * 256 + t] = dl[s];
  }
  __syncthreads();
  if (t < 64) {
    #pragma unroll 1
    for (int j = 1; j < 4; ++j) {
      u64 nb[16];
      #pragma unroll
      for (int s = 0; s < 16; ++s) nb[s] = mb[s * 256 + (t + 64 * j)];
      merge16(dl, nb);
    }
    u64* outp = part + (((size_t)n * PP + pb + t) * 4 + qq) * 16;
    #pragma unroll
    for (int s = 0; s < 16; ++s) outp[s] = dl[s];
  }
}

// ---------------- knn merge: 4 sorted-16 partial lists per row -> final idx ----------------
__global__ __launch_bounds__(256) void knnm_k(const u64* __restrict__ part,
                                              int* __restrict__ idx) {
  const int row = blockIdx.x * 256 + threadIdx.x;   // 0..32767
  const u64* p = part + (size_t)row * 64;
  u64 dl[16];
  #pragma unroll
  for (int s = 0; s < 16; ++s) dl[s] = p[s];
  #pragma unroll 1
  for (int j = 1; j < 4; ++j) {
    u64 nb[16];
    #pragma unroll
    for (int s = 0; s < 16; ++s) nb[s] = p[j * 16 + s];
    merge16(dl, nb);
  }
  #pragma unroll
  for (int s = 0; s < 16; ++s)
    idx[(size_t)row * KK + s] = (int)(dl[s] & 0xFFFFFFFFu);
}

// ---------------- conv (MFMA bf16): y = A @ w^T + bias, fused per-WG BN partial stats ----------------
// y stores are NONTEMPORAL (streaming, keep L2 for gather sources / weights / st).
template<int KIN, bool GATHER, bool BNRELU>
__global__ __launch_bounds__(256) void conv_k(const u16* __restrict__ in,
                                              const int* __restrict__ idxp,
                                              const u16* __restrict__ wb,
                                              const float* __restrict__ bias,
                                              const float* __restrict__ st,
                                              u16* __restrict__ yout,
                                              float* __restrict__ partials) {
  constexpr int NKB = KIN / 32;
  __shared__ float sred[4][4][32];
  const int t = threadIdx.x;
  const int wv = t >> 6, l = t & 63, hi = l >> 4, lo = l & 15;
  const int rbase = blockIdx.x * 256 + wv * 64;

  bf16x8 wf[4][NKB];
  #pragma unroll
  for (int ob = 0; ob < 4; ++ob)
    #pragma unroll
    for (int kb = 0; kb < NKB; ++kb)
      wf[ob][kb] = *(const bf16x8*)(wb + (size_t)(ob*16 + lo) * KIN + kb*32 + hi*8);

  int qv[4];
  if constexpr (GATHER) {
    #pragma unroll
    for (int rb = 0; rb < 4; ++rb) {
      const int g = (rbase + rb*16) >> 4;     // one point per 16-row block
      qv[rb] = idxp[g * KK + lo];
    }
  }

  f32x4 acc[4][4];
  #pragma unroll
  for (int a = 0; a < 4; ++a)
    #pragma unroll
    for (int b = 0; b < 4; ++b) { f32x4 z = {0.f, 0.f, 0.f, 0.f}; acc[a][b] = z; }

  #pragma unroll
  for (int kb = 0; kb < NKB; ++kb) {
    float sv[8], tv[8];
    if constexpr (BNRELU) {
      const int k0 = kb*32 + hi*8;
      *(float4*)&sv[0] = *(const float4*)(st + k0);
      *(float4*)&sv[4] = *(const float4*)(st + k0 + 4);
      *(float4*)&tv[0] = *(const float4*)(st + KIN + k0);
      *(float4*)&tv[4] = *(const float4*)(st + KIN + k0 + 4);
    }
    bf16x8 af[4];
    #pragma unroll
    for (int rb = 0; rb < 4; ++rb) {
      if constexpr (GATHER) {
        const int g  = (rbase + rb*16) >> 4;
        const int k0 = kb*32 + hi*8;
        const bf16x8 fc = *(const bf16x8*)(in + (size_t)g * CC + (k0 & 63));
        if (kb < 2) {
          af[rb] = fc;                                   // h[:, :64] = fc (broadcast rows)
        } else {
          const int nn = g >> 11;
          const bf16x8 fv = *(const bf16x8*)(in + (size_t)(nn * PP + qv[rb]) * CC + (k0 & 63));
          bf16x8 df;
          #pragma unroll
          for (int j = 0; j < 8; ++j)
            df[j] = (short)f2b(b2f((u16)fc[j]) - b2f((u16)fv[j]));
          af[rb] = df;
        }
      } else {
        const int row = rbase + rb*16 + lo;
        const bf16x8 rv = __builtin_nontemporal_load((const bf16x8*)(in + (size_t)row * KIN + kb*32 + hi*8));
        if constexpr (BNRELU) {
          bf16x8 tr;
          #pragma unroll
          for (int j = 0; j < 8; ++j) {
            const float x = fmaxf(b2f((u16)rv[j]) * sv[j] + tv[j], 0.f);
            tr[j] = (short)f2b(x);
          }
          af[rb] = tr;
        } else {
          af[rb] = rv;
        }
      }
    }
    #pragma unroll
    for (int ob = 0; ob < 4; ++ob)
      #pragma unroll
      for (int rb = 0; rb < 4; ++rb)
        acc[rb][ob] = __builtin_amdgcn_mfma_f32_16x16x32_bf16(wf[ob][kb], af[rb], acc[rb][ob], 0, 0, 0);
  }

  // epilogue: D[row=(l>>4)*4+reg -> out ch][col=l&15 -> A row]; nt-store + per-channel sum/sumsq
  float ssum[16], qsum[16];
  #pragma unroll
  for (int j = 0; j < 16; ++j) { ssum[j] = 0.f; qsum[j] = 0.f; }
  #pragma unroll
  for (int ob = 0; ob < 4; ++ob) {
    const int o0 = ob*16 + hi*4;
    const float4 bv = *(const float4*)(bias + o0);
    #pragma unroll
    for (int rb = 0; rb < 4; ++rb) {
      const int row = rbase + rb*16 + lo;
      const float v0 = acc[rb][ob][0] + bv.x;
      const float v1 = acc[rb][ob][1] + bv.y;
      const float v2 = acc[rb][ob][2] + bv.z;
      const float v3 = acc[rb][ob][3] + bv.w;
      u16x4 pk; pk[0] = f2b(v0); pk[1] = f2b(v1); pk[2] = f2b(v2); pk[3] = f2b(v3);
      __builtin_nontemporal_store(pk, (u16x4*)(yout + (size_t)row * CC + o0));
      ssum[ob*4+0] += v0; qsum[ob*4+0] += v0*v0;
      ssum[ob*4+1] += v1; qsum[ob*4+1] += v1*v1;
      ssum[ob*4+2] += v2; qsum[ob*4+2] += v2*v2;
      ssum[ob*4+3] += v3; qsum[ob*4+3] += v3*v3;
    }
  }
  #pragma unroll
  for (int m = 1; m < 16; m <<= 1) {
    #pragma unroll
    for (int j = 0; j < 16; ++j) {
      ssum[j] += __shfl_xor(ssum[j], m, 64);
      qsum[j] += __shfl_xor(qsum[j], m, 64);
    }
  }
  if (lo == 0) {
    #pragma unroll
    for (int j = 0; j < 16; ++j) {
      sred[wv][hi][j*2]   = ssum[j];
      sred[wv][hi][j*2+1] = qsum[j];
    }
  }
  __syncthreads();
  if (t < 128) {
    const int c = t & 63, half = t >> 6;
    const int slot = ((c >> 4) * 4 + (c & 3)) * 2 + half;   // ob*4+e
    const int h2 = (c >> 2) & 3;
    const float v = sred[0][h2][slot] + sred[1][h2][slot] + sred[2][h2][slot] + sred[3][h2][slot];
    partials[(size_t)blockIdx.x * 128 + half * 64 + c] = v;
  }
}

// ---------------- stage-1 reduce: nwg partial rows -> 64 rows ----------------
__global__ __launch_bounds__(256) void red1_k(const float* __restrict__ partials,
                                              float* __restrict__ out, int nwg) {
  __shared__ float accs[2][128];
  const int t = threadIdx.x, e = t & 127, h = t >> 7;
  float s = 0.f;
  for (int w = blockIdx.x + h * 64; w < nwg; w += 128)
    s += partials[(size_t)w * 128 + e];
  accs[h][e] = s;
  __syncthreads();
  if (t < 128) out[(size_t)blockIdx.x * 128 + t] = accs[0][t] + accs[1][t];
}

// ---------------- stage-2: 64 rows -> fused BN scale/bias ----------------
__global__ __launch_bounds__(128) void red2_k(const float* __restrict__ p2,
                                              const float* __restrict__ g,
                                              const float* __restrict__ be,
                                              float* __restrict__ st, float invM) {
  __shared__ float sq[128];
  const int t = threadIdx.x;            // element t: [0,64)=sum, [64,128)=sumsq
  float s = 0.f;
  #pragma unroll 8
  for (int w = 0; w < 64; ++w) s += p2[w * 128 + t];
  sq[t] = s;
  __syncthreads();
  if (t < 64) {
    const float S = sq[t], Q = sq[64 + t];
    const float m = S * invM;
    const float v = fmaxf(Q * invM - m * m, 0.f);
    const float sc = g[t] * rsqrtf(v + 1e-5f);
    st[t] = sc;
    st[64 + t] = be[t] - m * sc;
  }
}

// ---------------- final: bn2+relu, mean over K, + bn(shortcut), relu, (N,C,P) store ----------------
__global__ __launch_bounds__(256) void final_k(const u16* __restrict__ y2,
                                               const u16* __restrict__ ysc,
                                               const float* __restrict__ st2,
                                               const float* __restrict__ stS,
                                               float* __restrict__ out) {
  __shared__ float ot[64][68];
  const int b = blockIdx.x, t = threadIdx.x;
  const int n = b >> 5, p0 = (b & 31) * 64;
  const int phh = t >> 2, jh = t & 3, c0 = jh * 16;
  const int g = n * PP + p0 + phh;
  float acc[16];
  #pragma unroll
  for (int i = 0; i < 16; ++i) acc[i] = 0.f;
  float sv[16], tv[16];
  #pragma unroll
  for (int i = 0; i < 16; ++i) { sv[i] = st2[c0 + i]; tv[i] = st2[64 + c0 + i]; }
  for (int k = 0; k < KK; ++k) {
    const u16* rp = y2 + ((size_t)g * KK + k) * CC + c0;
    const bf16x8 v0 = __builtin_nontemporal_load((const bf16x8*)rp);
    const bf16x8 v1 = __builtin_nontemporal_load((const bf16x8*)(rp + 8));
    #pragma unroll
    for (int j = 0; j < 8; ++j) {
      acc[j]     += fmaxf(b2f((u16)v0[j]) * sv[j]     + tv[j],     0.f);
      acc[8 + j] += fmaxf(b2f((u16)v1[j]) * sv[8 + j] + tv[8 + j], 0.f);
    }
  }
  const u16* sp = ysc + (size_t)g * CC + c0;
  const bf16x8 s0 = *(const bf16x8*)sp;
  const bf16x8 s1 = *(const bf16x8*)(sp + 8);
  #pragma unroll
  for (int i = 0; i < 16; ++i) {
    const float scx = b2f((u16)(i < 8 ? s0[i] : s1[i - 8])) * stS[c0 + i] + stS[64 + c0 + i];
    ot[c0 + i][phh] = fmaxf(acc[i] * (1.f / 16.f) + scx, 0.f);
  }
  __syncthreads();
  const int c = t >> 2, pc = t & 3;
  const float* src = &ot[c][pc * 16];
  float* dst = out + (size_t)n * CC * PP + (size_t)c * PP + p0 + pc * 16;
  #pragma unroll
  for (int j = 0; j < 16; j += 4) *(float4*)(dst + j) = *(const float4*)(src + j);
}

// ---------------- host ----------------
extern "C" void kernel_launch(void* const* d_in, const int* in_sizes, int n_in,
                              void* d_out, int out_size, void* d_ws, size_t ws_size,
                              hipStream_t stream) {
  (void)in_sizes; (void)n_in; (void)out_size; (void)ws_size;
  const float* F   = (const float*)d_in[0];
  const float* w0  = (const float*)d_in[1];
  const float* b0  = (const float*)d_in[2];
  const float* g0  = (const float*)d_in[3];
  const float* be0 = (const float*)d_in[4];
  const float* w1  = (const float*)d_in[5];
  const float* b1  = (const float*)d_in[6];
  const float* g1  = (const float*)d_in[7];
  const float* be1 = (const float*)d_in[8];
  const float* w2  = (const float*)d_in[9];
  const float* b2  = (const float*)d_in[10];
  const float* g2  = (const float*)d_in[11];
  const float* be2 = (const float*)d_in[12];
  const float* wS  = (const float*)d_in[13];
  const float* bS  = (const float*)d_in[14];
  const float* gS  = (const float*)d_in[15];
  const float* beS = (const float*)d_in[16];

  char* ws = (char*)d_ws;
  size_t off = 0;
  auto carve = [&](size_t bytes) -> void* {
    void* p = ws + off;
    off += (bytes + 255) & ~(size_t)255;
    return p;
  };
  u16*   Xb       = (u16*)  carve((size_t)NPTS * CC * 2);       // 4.2 MB  (h plane)
  u16*   X3       = (u16*)  carve((size_t)NPTS * 128 * 2);      // 8.4 MB  (m|l planes)
  float* rr       = (float*)carve((size_t)NPTS * 4);            // 128 KB
  int*   idx      = (int*)  carve((size_t)NPTS * KK * 4);       // 2 MB
  u16*   wb0      = (u16*)  carve(8192 * 2);
  u16*   wb1      = (u16*)  carve(4096 * 2);
  u16*   wb2      = (u16*)  carve(4096 * 2);
  u16*   wbs      = (u16*)  carve(4096 * 2);
  u16*   y        = (u16*)  carve((size_t)MROWS * CC * 2);      // 67 MB
  u16*   ysc      = (u16*)  carve((size_t)NPTS * CC * 2);       // 4.2 MB
  float* partials = (float*)carve((size_t)2048 * 128 * 4);      // 1 MB
  float* p2       = (float*)carve((size_t)64 * 128 * 4);        // 32 KB
  float* st0      = (float*)carve(128 * 4);
  float* st1      = (float*)carve(128 * 4);
  float* st2      = (float*)carve(128 * 4);
  float* stS      = (float*)carve(128 * 4);

  // knn partial lists (32768 rows x 4 x 16 u64 = 16 MB) alias the y buffer:
  // written by knn_k, consumed by knnm_k, both strictly before conv0 writes y.
  u64* part = (u64*)y;

  prep_k<<<NPTS / 256, 256, 0, stream>>>(F, Xb, X3, rr);
  cvtw_k<<<80, 256, 0, stream>>>(w0, w1, w2, wS, wb0, wb1, wb2, wbs);
  knn_k<<<NB * 32 * 4, 256, 0, stream>>>(Xb, X3, rr, part);
  knnm_k<<<NPTS / 256, 256, 0, stream>>>(part, idx);

  conv_k<128, true,  false><<<MROWS / 256, 256, 0, stream>>>(Xb, idx, wb0, b0, nullptr, y, partials);
  red1_k<<<64, 256, 0, stream>>>(partials, p2, MROWS / 256);
  red2_k<<<1, 128, 0, stream>>>(p2, g0, be0, st0, 1.f / (float)MROWS);

  conv_k<64, false, true><<<MROWS / 256, 256, 0, stream>>>(y, nullptr, wb1, b1, st0, y, partials);
  red1_k<<<64, 256, 0, stream>>>(partials, p2, MROWS / 256);
  red2_k<<<1, 128, 0, stream>>>(p2, g1, be1, st1, 1.f / (float)MROWS);

  conv_k<64, false, true><<<MROWS / 256, 256, 0, stream>>>(y, nullptr, wb2, b2, st1, y, partials);
  red1_k<<<64, 256, 0, stream>>>(partials, p2, MROWS / 256);
  red2_k<<<1, 128, 0, stream>>>(p2, g2, be2, st2, 1.f / (float)MROWS);

  conv_k<64, false, false><<<NPTS / 256, 256, 0, stream>>>(Xb, nullptr, wbs, bS, nullptr, ysc, partials);
  red1_k<<<64, 256, 0, stream>>>(partials, p2, NPTS / 256);
  red2_k<<<1, 128, 0, stream>>>(p2, gS, beS, stS, 1.f / (float)NPTS);

  final_k<<<NB * (PP / 64), 256, 0, stream>>>(y, ysc, st2, stS, (float*)d_out);
}

// Round 15
// 386.300 us; speedup vs baseline: 1.1798x; 1.1798x over previous
//
#include <hip/hip_runtime.h>

using u16    = unsigned short;
using u32    = unsigned int;
using u64    = unsigned long long;
using bf16x8 = __attribute__((ext_vector_type(8))) short;
using f32x4  = __attribute__((ext_vector_type(4))) float;
using u16x4  = __attribute__((ext_vector_type(4))) u16;

#define NB   16
#define PP   2048
#define CC   64
#define KK   16
#define MROWS (NB*PP*KK)   /* 524288 */
#define NPTS  (NB*PP)      /* 32768  */

__device__ __forceinline__ float b2f(u16 u) { return __uint_as_float(((unsigned)u) << 16); }
__device__ __forceinline__ u16 f2b(float f) {
  unsigned u = __float_as_uint(f);
  return (u16)((u + 0x7fffu + ((u >> 16) & 1u)) >> 16);
}

// order-preserving (d, qi) -> u64 key: smaller key == smaller d, tie -> smaller qi (EXACT)
__device__ __forceinline__ u64 dkey(float d, int qi) {
  unsigned u = __float_as_uint(d);
  u = u ^ (((unsigned)((int)u >> 31)) | 0x80000000u);
  return ((u64)u << 32) | (unsigned)qi;
}

template<bool UP>
__device__ __forceinline__ void ce(u64 &a, u64 &b) {
  const bool lt = a < b;
  const u64 lo = lt ? a : b;
  const u64 hi = lt ? b : a;
  if (UP) { a = lo; b = hi; } else { a = hi; b = lo; }
}

// full bitonic sort, ascending
__device__ __forceinline__ void sort16(u64 (&v)[16]) {
  #pragma unroll
  for (int k = 2; k <= 16; k <<= 1) {
    #pragma unroll
    for (int j = k >> 1; j > 0; j >>= 1) {
      #pragma unroll
      for (int i = 0; i < 16; ++i) {
        const int l = i ^ j;
        if (l > i) {
          if ((i & k) == 0) ce<true>(v[i], v[l]);
          else              ce<false>(v[i], v[l]);
        }
      }
    }
  }
}

// dl (sorted asc) <- lowest 16 of union(dl, nb), nb sorted asc; result sorted asc
__device__ __forceinline__ void merge16(u64 (&dl)[16], const u64 (&nb)[16]) {
  u64 t[16];
  #pragma unroll
  for (int s = 0; s < 16; ++s) {
    const u64 a = dl[s], b = nb[15 - s];
    t[s] = a < b ? a : b;                 // bitonic sequence of the 16 smallest
  }
  #pragma unroll
  for (int j = 8; j > 0; j >>= 1) {
    #pragma unroll
    for (int i = 0; i < 16; ++i) {
      const int l = i ^ j;
      if (l > i) ce<true>(t[i], t[l]);
    }
  }
  #pragma unroll
  for (int s = 0; s < 16; ++s) dl[s] = t[s];
}

// ---------------- prep: features (N,C,P) -> Xb (h plane, bf16), X3 (m,l planes), r ----------------
// 3-way bf16 split: x = h + m + l + eps, |eps| <~ 2^-27 |x| (each residual exact by Sterbenz).
__global__ __launch_bounds__(256) void prep_k(const float* __restrict__ F,
                                              u16* __restrict__ Xb,
                                              u16* __restrict__ X3,
                                              float* __restrict__ r) {
  int gidx = blockIdx.x * 256 + threadIdx.x;      // 0..32767
  int n = gidx >> 11, p = gidx & 2047;
  const float* src = F + (size_t)n * CC * PP + p;
  float rr = 0.f;
  u16 ha[CC], ma[CC], la[CC];
  #pragma unroll
  for (int c = 0; c < CC; ++c) {
    const float x = src[(size_t)c * PP];
    rr += x * x;
    const u16 h = f2b(x);
    const float eh = x - b2f(h);          // exact
    const u16 m = f2b(eh);
    const float el = eh - b2f(m);         // exact
    const u16 lo_ = f2b(el);
    ha[c] = h; ma[c] = m; la[c] = lo_;
  }
  u16* db = Xb + (size_t)gidx * CC;
  u16* d3 = X3 + (size_t)gidx * 128;
  #pragma unroll
  for (int c = 0; c < CC; c += 8) {
    bf16x8 wh, wm, wl;
    #pragma unroll
    for (int j = 0; j < 8; ++j) { wh[j] = (short)ha[c+j]; wm[j] = (short)ma[c+j]; wl[j] = (short)la[c+j]; }
    *(bf16x8*)(db + c)      = wh;
    *(bf16x8*)(d3 + c)      = wm;
    *(bf16x8*)(d3 + 64 + c) = wl;
  }
  r[gidx] = rr;
}

// ---------------- weight fp32 -> bf16 ----------------
__global__ __launch_bounds__(256) void cvtw_k(const float* __restrict__ w0, const float* __restrict__ w1,
                                              const float* __restrict__ w2, const float* __restrict__ wsb,
                                              u16* __restrict__ b0, u16* __restrict__ b1,
                                              u16* __restrict__ b2, u16* __restrict__ bs) {
  int i = blockIdx.x * 256 + threadIdx.x;         // 20480 total
  if (i < 8192)        b0[i]          = f2b(w0[i]);
  else if (i < 12288)  b1[i - 8192]   = f2b(w1[i - 8192]);
  else if (i < 16384)  b2[i - 12288]  = f2b(w2[i - 12288]);
  else if (i < 20480)  bs[i - 16384]  = f2b(wsb[i - 16384]);
}

// ---------------- fused KNN v9 (r12 verbatim): 256-thread WG, split-bf16 MFMA GEMM + u64 top-16 ---
// grid 2048: n = bx>>7, pb = ((bx>>2)&31)*64, qq = bx&3 -> q in [qq*512, +512), 4 tiles of 128 q.
// 4 waves: wave w owns p-rows w*16..+15 x all 128 q -> acc[8] (8 subtiles of 16x16).
// A-fragments loaded ONCE from global into registers (no Xp LDS). LDS = XqL [128][200] bf16 only;
// D [64][132] f32 and the merge area overlay it.
__global__ __launch_bounds__(256)
void knn_k(const u16* __restrict__ Xb, const u16* __restrict__ X3,
           const float* __restrict__ r, u64* __restrict__ part) {
  __shared__ u16 XqL[128 * 200];                // 51.2 KB; D + merge area overlay
  float* D  = (float*)XqL;                      // [64][132] f32 (33.8 KB)
  u64*   mb = (u64*)XqL;                        // merge area (32 KB)

  const int n  = blockIdx.x >> 7;
  const int pb = ((blockIdx.x >> 2) & 31) * 64;
  const int qq = blockIdx.x & 3;
  const int qstart = qq * 512;
  const int t  = threadIdx.x;
  const int l  = t & 63, w = t >> 6;            // wave index 0..3
  const int lo = l & 15, hi4 = l >> 4;
  const int prow = t & 63;                      // select: own row
  const int qh2  = t >> 6;                      // select: quarter of tile
  const int u4   = (prow & 7) * 4;              // select-side swizzle key

  const u16*  Xbn = Xb + (size_t)(n * PP) * CC;
  const u16*  X3n = X3 + (size_t)(n * PP) * 128;
  const float* rb = r + n * PP;

  // A-fragments direct from global, once (row = pb + w*16 + lo)
  bf16x8 ah[2], am[2], al[2];
  {
    const size_t rowb = (size_t)(pb + w * 16 + lo);
    #pragma unroll
    for (int kb = 0; kb < 2; ++kb) {
      ah[kb] = *(const bf16x8*)(Xbn + rowb * CC  + kb * 32 + hi4 * 8);
      am[kb] = *(const bf16x8*)(X3n + rowb * 128 + kb * 32 + hi4 * 8);
      al[kb] = *(const bf16x8*)(X3n + rowb * 128 + 64 + kb * 32 + hi4 * 8);
    }
  }

  u64 dl[16];
  #pragma unroll
  for (int s = 0; s < 16; ++s) dl[s] = ~0ULL;

  #pragma unroll 1
  for (int qb = qstart; qb < qstart + 512; qb += 128) {
    __syncthreads();                    // previous select readers done
    { // stage XqL [128][200]: h 1024 units (4/thread), m|l 2048 units (8/thread)
      #pragma unroll
      for (int k = 0; k < 4; ++k) {
        const int u = t + k * 256;
        const int row = u >> 3, unit = u & 7;
        *(bf16x8*)(XqL + row * 200 + unit * 8) =
          *(const bf16x8*)(Xbn + (size_t)(qb + row) * CC + unit * 8);
      }
      #pragma unroll
      for (int k = 0; k < 8; ++k) {
        const int u = t + k * 256;
        const int row = u >> 4, unit = u & 15;
        *(bf16x8*)(XqL + row * 200 + 64 + unit * 8) =
          *(const bf16x8*)(X3n + (size_t)(qb + row) * 128 + unit * 8);
      }
    }
    __syncthreads();

    f32x4 acc[8];
    #pragma unroll
    for (int Q = 0; Q < 8; ++Q) { f32x4 z = {0.f, 0.f, 0.f, 0.f}; acc[Q] = z; }

    #pragma unroll
    for (int Q = 0; Q < 8; ++Q) {
      const int qrow = Q * 16 + lo;
      #pragma unroll
      for (int kb = 0; kb < 2; ++kb) {
        const int base = qrow * 200 + kb * 32 + hi4 * 8;
        const bf16x8 bh = *(const bf16x8*)(XqL + base);
        const bf16x8 bm = *(const bf16x8*)(XqL + base + 64);
        const bf16x8 bl = *(const bf16x8*)(XqL + base + 128);
        acc[Q] = __builtin_amdgcn_mfma_f32_16x16x32_bf16(ah[kb], bh, acc[Q], 0, 0, 0);
        acc[Q] = __builtin_amdgcn_mfma_f32_16x16x32_bf16(am[kb], bh, acc[Q], 0, 0, 0);
        acc[Q] = __builtin_amdgcn_mfma_f32_16x16x32_bf16(ah[kb], bm, acc[Q], 0, 0, 0);
        acc[Q] = __builtin_amdgcn_mfma_f32_16x16x32_bf16(al[kb], bh, acc[Q], 0, 0, 0);
        acc[Q] = __builtin_amdgcn_mfma_f32_16x16x32_bf16(ah[kb], bl, acc[Q], 0, 0, 0);
        acc[Q] = __builtin_amdgcn_mfma_f32_16x16x32_bf16(am[kb], bm, acc[Q], 0, 0, 0);
      }
    }
    __syncthreads();                    // all XqL fragment reads done -> overlay D

    { // D-write: p = w*16 + hi4*4 + e (MFMA row-reg), q = Q*16 + lo (MFMA col)
      #pragma unroll
      for (int Q = 0; Q < 8; ++Q) {
        const int qloc  = Q * 16 + lo;
        const int qglob = qb + qloc;
        const float rq  = rb[qglob];
        const int bidx = qloc >> 2, qrem = qloc & 3;
        #pragma unroll
        for (int e = 0; e < 4; ++e) {
          const int p = w * 16 + hi4 * 4 + e;
          float d = rq - 2.f * acc[Q][e];
          if (qglob == pb + p) d = 3.0e38f;
          const int swz = ((bidx ^ ((p & 7) << 2)) << 2) + qrem;
          D[p * 132 + swz] = d;
        }
      }
    }
    __syncthreads();

    // select: thread scans row prow, blocks b = qh2*8..+7 as two 16-key batches
    #pragma unroll
    for (int half = 0; half < 2; ++half) {
      u64 nb[16];
      const float* drow = D + (size_t)prow * 132;
      #pragma unroll
      for (int bb = 0; bb < 4; ++bb) {
        const int b = qh2 * 8 + half * 4 + bb;
        const float4 dv = *(const float4*)(drow + ((b ^ u4) * 4));
        const int qg = qb + b * 4;
        nb[bb*4+0] = dkey(dv.x, qg+0);
        nb[bb*4+1] = dkey(dv.y, qg+1);
        nb[bb*4+2] = dkey(dv.z, qg+2);
        nb[bb*4+3] = dkey(dv.w, qg+3);
      }
      sort16(nb);
      merge16(dl, nb);
    }
  }

  // merge 4 partial sorted lists per row (threads t, t+64, t+128, t+192) via LDS
  __syncthreads();
  {
    #pragma unroll
    for (int s = 0; s < 16; ++s) mb[s * 256 + t] = dl[s];
  }
  __syncthreads();
  if (t < 64) {
    #pragma unroll 1
    for (int j = 1; j < 4; ++j) {
      u64 nb[16];
      #pragma unroll
      for (int s = 0; s < 16; ++s) nb[s] = mb[s * 256 + (t + 64 * j)];
      merge16(dl, nb);
    }
    u64* outp = part + (((size_t)n * PP + pb + t) * 4 + qq) * 16;
    #pragma unroll
    for (int s = 0; s < 16; ++s) outp[s] = dl[s];
  }
}

// ---------------- knn merge: 4 sorted-16 partial lists per row -> final idx ----------------
__global__ __launch_bounds__(256) void knnm_k(const u64* __restrict__ part,
                                              int* __restrict__ idx) {
  const int row = blockIdx.x * 256 + threadIdx.x;   // 0..32767
  const u64* p = part + (size_t)row * 64;
  u64 dl[16];
  #pragma unroll
  for (int s = 0; s < 16; ++s) dl[s] = p[s];
  #pragma unroll 1
  for (int j = 1; j < 4; ++j) {
    u64 nb[16];
    #pragma unroll
    for (int s = 0; s < 16; ++s) nb[s] = p[j * 16 + s];
    merge16(dl, nb);
  }
  #pragma unroll
  for (int s = 0; s < 16; ++s)
    idx[(size_t)row * KK + s] = (int)(dl[s] & 0xFFFFFFFFu);
}

// ---------------- conv (MFMA bf16): y = A @ w^T + bias, fused per-WG BN partial stats ----------------
template<int KIN, bool GATHER, bool BNRELU>
__global__ __launch_bounds__(256) void conv_k(const u16* __restrict__ in,
                                              const int* __restrict__ idxp,
                                              const u16* __restrict__ wb,
                                              const float* __restrict__ bias,
                                              const float* __restrict__ st,
                                              u16* __restrict__ yout,
                                              float* __restrict__ partials) {
  constexpr int NKB = KIN / 32;
  __shared__ float sred[4][4][32];
  const int t = threadIdx.x;
  const int wv = t >> 6, l = t & 63, hi = l >> 4, lo = l & 15;
  const int rbase = blockIdx.x * 256 + wv * 64;

  bf16x8 wf[4][NKB];
  #pragma unroll
  for (int ob = 0; ob < 4; ++ob)
    #pragma unroll
    for (int kb = 0; kb < NKB; ++kb)
      wf[ob][kb] = *(const bf16x8*)(wb + (size_t)(ob*16 + lo) * KIN + kb*32 + hi*8);

  int qv[4];
  if constexpr (GATHER) {
    #pragma unroll
    for (int rb = 0; rb < 4; ++rb) {
      const int g = (rbase + rb*16) >> 4;     // one point per 16-row block
      qv[rb] = idxp[g * KK + lo];
    }
  }

  f32x4 acc[4][4];
  #pragma unroll
  for (int a = 0; a < 4; ++a)
    #pragma unroll
    for (int b = 0; b < 4; ++b) { f32x4 z = {0.f, 0.f, 0.f, 0.f}; acc[a][b] = z; }

  #pragma unroll
  for (int kb = 0; kb < NKB; ++kb) {
    float sv[8], tv[8];
    if constexpr (BNRELU) {
      const int k0 = kb*32 + hi*8;
      *(float4*)&sv[0] = *(const float4*)(st + k0);
      *(float4*)&sv[4] = *(const float4*)(st + k0 + 4);
      *(float4*)&tv[0] = *(const float4*)(st + KIN + k0);
      *(float4*)&tv[4] = *(const float4*)(st + KIN + k0 + 4);
    }
    bf16x8 af[4];
    #pragma unroll
    for (int rb = 0; rb < 4; ++rb) {
      if constexpr (GATHER) {
        const int g  = (rbase + rb*16) >> 4;
        const int k0 = kb*32 + hi*8;
        const bf16x8 fc = *(const bf16x8*)(in + (size_t)g * CC + (k0 & 63));
        if (kb < 2) {
          af[rb] = fc;                                   // h[:, :64] = fc (broadcast rows)
        } else {
          const int nn = g >> 11;
          const bf16x8 fv = *(const bf16x8*)(in + (size_t)(nn * PP + qv[rb]) * CC + (k0 & 63));
          bf16x8 df;
          #pragma unroll
          for (int j = 0; j < 8; ++j)
            df[j] = (short)f2b(b2f((u16)fc[j]) - b2f((u16)fv[j]));
          af[rb] = df;
        }
      } else {
        const int row = rbase + rb*16 + lo;
        const bf16x8 rv = *(const bf16x8*)(in + (size_t)row * KIN + kb*32 + hi*8);
        if constexpr (BNRELU) {
          bf16x8 tr;
          #pragma unroll
          for (int j = 0; j < 8; ++j) {
            const float x = fmaxf(b2f((u16)rv[j]) * sv[j] + tv[j], 0.f);
            tr[j] = (short)f2b(x);
          }
          af[rb] = tr;
        } else {
          af[rb] = rv;
        }
      }
    }
    #pragma unroll
    for (int ob = 0; ob < 4; ++ob)
      #pragma unroll
      for (int rb = 0; rb < 4; ++rb)
        acc[rb][ob] = __builtin_amdgcn_mfma_f32_16x16x32_bf16(wf[ob][kb], af[rb], acc[rb][ob], 0, 0, 0);
  }

  // epilogue: D[row=(l>>4)*4+reg -> out ch][col=l&15 -> A row]; store + per-channel sum/sumsq
  float ssum[16], qsum[16];
  #pragma unroll
  for (int j = 0; j < 16; ++j) { ssum[j] = 0.f; qsum[j] = 0.f; }
  #pragma unroll
  for (int ob = 0; ob < 4; ++ob) {
    const int o0 = ob*16 + hi*4;
    const float4 bv = *(const float4*)(bias + o0);
    #pragma unroll
    for (int rb = 0; rb < 4; ++rb) {
      const int row = rbase + rb*16 + lo;
      const float v0 = acc[rb][ob][0] + bv.x;
      const float v1 = acc[rb][ob][1] + bv.y;
      const float v2 = acc[rb][ob][2] + bv.z;
      const float v3 = acc[rb][ob][3] + bv.w;
      u16x4 pk; pk[0] = f2b(v0); pk[1] = f2b(v1); pk[2] = f2b(v2); pk[3] = f2b(v3);
      *(u16x4*)(yout + (size_t)row * CC + o0) = pk;
      ssum[ob*4+0] += v0; qsum[ob*4+0] += v0*v0;
      ssum[ob*4+1] += v1; qsum[ob*4+1] += v1*v1;
      ssum[ob*4+2] += v2; qsum[ob*4+2] += v2*v2;
      ssum[ob*4+3] += v3; qsum[ob*4+3] += v3*v3;
    }
  }
  #pragma unroll
  for (int m = 1; m < 16; m <<= 1) {
    #pragma unroll
    for (int j = 0; j < 16; ++j) {
      ssum[j] += __shfl_xor(ssum[j], m, 64);
      qsum[j] += __shfl_xor(qsum[j], m, 64);
    }
  }
  if (lo == 0) {
    #pragma unroll
    for (int j = 0; j < 16; ++j) {
      sred[wv][hi][j*2]   = ssum[j];
      sred[wv][hi][j*2+1] = qsum[j];
    }
  }
  __syncthreads();
  if (t < 128) {
    const int c = t & 63, half = t >> 6;
    const int slot = ((c >> 4) * 4 + (c & 3)) * 2 + half;   // ob*4+e
    const int h2 = (c >> 2) & 3;
    const float v = sred[0][h2][slot] + sred[1][h2][slot] + sred[2][h2][slot] + sred[3][h2][slot];
    partials[(size_t)blockIdx.x * 128 + half * 64 + c] = v;
  }
}

// ---------------- stage-1 reduce: nwg partial rows -> 64 rows ----------------
__global__ __launch_bounds__(256) void red1_k(const float* __restrict__ partials,
                                              float* __restrict__ out, int nwg) {
  __shared__ float accs[2][128];
  const int t = threadIdx.x, e = t & 127, h = t >> 7;
  float s = 0.f;
  for (int w = blockIdx.x + h * 64; w < nwg; w += 128)
    s += partials[(size_t)w * 128 + e];
  accs[h][e] = s;
  __syncthreads();
  if (t < 128) out[(size_t)blockIdx.x * 128 + t] = accs[0][t] + accs[1][t];
}

// ---------------- stage-2: 64 rows -> fused BN scale/bias ----------------
__global__ __launch_bounds__(128) void red2_k(const float* __restrict__ p2,
                                              const float* __restrict__ g,
                                              const float* __restrict__ be,
                                              float* __restrict__ st, float invM) {
  __shared__ float sq[128];
  const int t = threadIdx.x;            // element t: [0,64)=sum, [64,128)=sumsq
  float s = 0.f;
  #pragma unroll 8
  for (int w = 0; w < 64; ++w) s += p2[w * 128 + t];
  sq[t] = s;
  __syncthreads();
  if (t < 64) {
    const float S = sq[t], Q = sq[64 + t];
    const float m = S * invM;
    const float v = fmaxf(Q * invM - m * m, 0.f);
    const float sc = g[t] * rsqrtf(v + 1e-5f);
    st[t] = sc;
    st[64 + t] = be[t] - m * sc;
  }
}

// ---------------- final: bn2+relu, mean over K, + bn(shortcut), relu, (N,C,P) store ----------------
__global__ __launch_bounds__(256) void final_k(const u16* __restrict__ y2,
                                               const u16* __restrict__ ysc,
                                               const float* __restrict__ st2,
                                               const float* __restrict__ stS,
                                               float* __restrict__ out) {
  __shared__ float ot[64][68];
  const int b = blockIdx.x, t = threadIdx.x;
  const int n = b >> 5, p0 = (b & 31) * 64;
  const int phh = t >> 2, jh = t & 3, c0 = jh * 16;
  const int g = n * PP + p0 + phh;
  float acc[16];
  #pragma unroll
  for (int i = 0; i < 16; ++i) acc[i] = 0.f;
  float sv[16], tv[16];
  #pragma unroll
  for (int i = 0; i < 16; ++i) { sv[i] = st2[c0 + i]; tv[i] = st2[64 + c0 + i]; }
  for (int k = 0; k < KK; ++k) {
    const u16* rp = y2 + ((size_t)g * KK + k) * CC + c0;
    const bf16x8 v0 = *(const bf16x8*)rp;
    const bf16x8 v1 = *(const bf16x8*)(rp + 8);
    #pragma unroll
    for (int j = 0; j < 8; ++j) {
      acc[j]     += fmaxf(b2f((u16)v0[j]) * sv[j]     + tv[j],     0.f);
      acc[8 + j] += fmaxf(b2f((u16)v1[j]) * sv[8 + j] + tv[8 + j], 0.f);
    }
  }
  const u16* sp = ysc + (size_t)g * CC + c0;
  const bf16x8 s0 = *(const bf16x8*)sp;
  const bf16x8 s1 = *(const bf16x8*)(sp + 8);
  #pragma unroll
  for (int i = 0; i < 16; ++i) {
    const float scx = b2f((u16)(i < 8 ? s0[i] : s1[i - 8])) * stS[c0 + i] + stS[64 + c0 + i];
    ot[c0 + i][phh] = fmaxf(acc[i] * (1.f / 16.f) + scx, 0.f);
  }
  __syncthreads();
  const int c = t >> 2, pc = t & 3;
  const float* src = &ot[c][pc * 16];
  float* dst = out + (size_t)n * CC * PP + (size_t)c * PP + p0 + pc * 16;
  #pragma unroll
  for (int j = 0; j < 16; j += 4) *(float4*)(dst + j) = *(const float4*)(src + j);
}

// ---------------- host ----------------
extern "C" void kernel_launch(void* const* d_in, const int* in_sizes, int n_in,
                              void* d_out, int out_size, void* d_ws, size_t ws_size,
                              hipStream_t stream) {
  (void)in_sizes; (void)n_in; (void)out_size; (void)ws_size;
  const float* F   = (const float*)d_in[0];
  const float* w0  = (const float*)d_in[1];
  const float* b0  = (const float*)d_in[2];
  const float* g0  = (const float*)d_in[3];
  const float* be0 = (const float*)d_in[4];
  const float* w1  = (const float*)d_in[5];
  const float* b1  = (const float*)d_in[6];
  const float* g1  = (const float*)d_in[7];
  const float* be1 = (const float*)d_in[8];
  const float* w2  = (const float*)d_in[9];
  const float* b2  = (const float*)d_in[10];
  const float* g2  = (const float*)d_in[11];
  const float* be2 = (const float*)d_in[12];
  const float* wS  = (const float*)d_in[13];
  const float* bS  = (const float*)d_in[14];
  const float* gS  = (const float*)d_in[15];
  const float* beS = (const float*)d_in[16];

  char* ws = (char*)d_ws;
  size_t off = 0;
  auto carve = [&](size_t bytes) -> void* {
    void* p = ws + off;
    off += (bytes + 255) & ~(size_t)255;
    return p;
  };
  u16*   Xb       = (u16*)  carve((size_t)NPTS * CC * 2);       // 4.2 MB  (h plane)
  u16*   X3       = (u16*)  carve((size_t)NPTS * 128 * 2);      // 8.4 MB  (m|l planes)
  float* rr       = (float*)carve((size_t)NPTS * 4);            // 128 KB
  int*   idx      = (int*)  carve((size_t)NPTS * KK * 4);       // 2 MB
  u16*   wb0      = (u16*)  carve(8192 * 2);
  u16*   wb1      = (u16*)  carve(4096 * 2);
  u16*   wb2      = (u16*)  carve(4096 * 2);
  u16*   wbs      = (u16*)  carve(4096 * 2);
  u16*   y        = (u16*)  carve((size_t)MROWS * CC * 2);      // 67 MB
  u16*   ysc      = (u16*)  carve((size_t)NPTS * CC * 2);       // 4.2 MB
  float* partials = (float*)carve((size_t)2048 * 128 * 4);      // 1 MB
  float* p2       = (float*)carve((size_t)64 * 128 * 4);        // 32 KB
  float* st0      = (float*)carve(128 * 4);
  float* st1      = (float*)carve(128 * 4);
  float* st2      = (float*)carve(128 * 4);
  float* stS      = (float*)carve(128 * 4);

  // knn partial lists (32768 rows x 4 x 16 u64 = 16 MB) alias the y buffer:
  // written by knn_k, consumed by knnm_k, both strictly before conv0 writes y.
  u64* part = (u64*)y;

  prep_k<<<NPTS / 256, 256, 0, stream>>>(F, Xb, X3, rr);
  cvtw_k<<<80, 256, 0, stream>>>(w0, w1, w2, wS, wb0, wb1, wb2, wbs);
  knn_k<<<NB * 32 * 4, 256, 0, stream>>>(Xb, X3, rr, part);
  knnm_k<<<NPTS / 256, 256, 0, stream>>>(part, idx);

  conv_k<128, true,  false><<<MROWS / 256, 256, 0, stream>>>(Xb, idx, wb0, b0, nullptr, y, partials);
  red1_k<<<64, 256, 0, stream>>>(partials, p2, MROWS / 256);
  red2_k<<<1, 128, 0, stream>>>(p2, g0, be0, st0, 1.f / (float)MROWS);

  conv_k<64, false, true><<<MROWS / 256, 256, 0, stream>>>(y, nullptr, wb1, b1, st0, y, partials);
  red1_k<<<64, 256, 0, stream>>>(partials, p2, MROWS / 256);
  red2_k<<<1, 128, 0, stream>>>(p2, g1, be1, st1, 1.f / (float)MROWS);

  conv_k<64, false, true><<<MROWS / 256, 256, 0, stream>>>(y, nullptr, wb2, b2, st1, y, partials);
  red1_k<<<64, 256, 0, stream>>>(partials, p2, MROWS / 256);
  red2_k<<<1, 128, 0, stream>>>(p2, g2, be2, st2, 1.f / (float)MROWS);

  conv_k<64, false, false><<<NPTS / 256, 256, 0, stream>>>(Xb, nullptr, wbs, bS, nullptr, ysc, partials);
  red1_k<<<64, 256, 0, stream>>>(partials, p2, NPTS / 256);
  red2_k<<<1, 128, 0, stream>>>(p2, gS, beS, stS, 1.f / (float)NPTS);

  final_k<<<NB * (PP / 64), 256, 0, stream>>>(y, ysc, st2, stS, (float*)d_out);
}